// Round 1
// baseline (457.478 us; speedup 1.0000x reference)
//
#include <hip/hip_runtime.h>
#include <stdint.h>

// DenseGraphAttentionHead, N=8192, IN=512, OUT=256, ~50% dense mask (int32 0/1).
//
// Strategy:
//   k_convert_w : W_w f32 [256][512] -> bf16 (row-major; B-operand reads are
//                 8 contiguous k per lane).
//   k_wh        : Wh = nodes@W^T + b via mfma_f32_16x16x32_bf16.
//                 Stores Wh^T bf16 [256][8192] (so PV B-frags are contiguous
//                 16B loads) and s1/s2 f32 [8192] computed from the f32
//                 accumulator (full precision scores).
//   k_attn      : fused masked-softmax @ Wh. Scores are bounded (|s|<~3) so
//                 exp needs no max subtraction -> single pass, no rescaling.
//                 256 blocks x 512 thr (8 waves = 2 Mgrp x 4 Ngrp), BM=32.
//                 Per k-step(32): lane loads 8 mask ints + 8 s2 f32, builds
//                 bf16 P fragment in-register, 4x MFMA vs Wh^T tiles, f32
//                 accum; den accumulated in f32; divide in epilogue.
//
// MFMA conventions (gfx950, learn_hip m89-verified):
//   A frag: lane&15 = m, 8 k-values at (lane>>4)*8 + i
//   B frag: lane&15 = n, same k order (A/B pair positionally -> any
//           consistent per-lane k order is correct)
//   D: col = lane&15, row = (lane>>4)*4 + reg

#define NN 8192
#define IND 512
#define OUTD 256
#define NEG_SLOPE 0.2f

typedef __attribute__((ext_vector_type(8))) short short8;
typedef __attribute__((ext_vector_type(4))) short short4v;
typedef __attribute__((ext_vector_type(4))) float f32x4;
typedef __attribute__((ext_vector_type(4))) int i32x4;

static __device__ __forceinline__ short bf16_rne(float f) {
  uint32_t u = __builtin_bit_cast(uint32_t, f);
  u += 0x7FFFu + ((u >> 16) & 1u);
  return (short)(u >> 16);
}

extern "C" __global__ __launch_bounds__(256) void k_convert_w(
    const float* __restrict__ W, short* __restrict__ Wbf) {
  int i = blockIdx.x * 256 + threadIdx.x;  // 32768 threads, 4 elems each
  f32x4 v = ((const f32x4*)W)[i];
  short4v o;
  o[0] = bf16_rne(v[0]); o[1] = bf16_rne(v[1]);
  o[2] = bf16_rne(v[2]); o[3] = bf16_rne(v[3]);
  ((short4v*)Wbf)[i] = o;
}

extern "C" __global__ __launch_bounds__(128) void k_wh(
    const float* __restrict__ nodes, const short* __restrict__ Wbf,
    const float* __restrict__ Wb, const float* __restrict__ a1w,
    const float* __restrict__ a1b, const float* __restrict__ a2w,
    const float* __restrict__ a2b, short* __restrict__ WhT,
    float* __restrict__ s1, float* __restrict__ s2) {
  const int tid = threadIdx.x;
  const int w = tid >> 6, lane = tid & 63, g = lane >> 4, m = lane & 15;
  const int rowbase = blockIdx.x * 32 + w * 16;  // 256 blocks x 2 waves

  f32x4 acc[16];
#pragma unroll
  for (int nf = 0; nf < 16; ++nf) acc[nf] = (f32x4){0.f, 0.f, 0.f, 0.f};

  const float* arow = nodes + (size_t)(rowbase + m) * IND;
  for (int k0 = 0; k0 < IND; k0 += 32) {
    const int ko = k0 + g * 8;
    f32x4 x0 = *(const f32x4*)(arow + ko);
    f32x4 x1 = *(const f32x4*)(arow + ko + 4);
    short8 af;
    af[0] = bf16_rne(x0[0]); af[1] = bf16_rne(x0[1]);
    af[2] = bf16_rne(x0[2]); af[3] = bf16_rne(x0[3]);
    af[4] = bf16_rne(x1[0]); af[5] = bf16_rne(x1[1]);
    af[6] = bf16_rne(x1[2]); af[7] = bf16_rne(x1[3]);
#pragma unroll
    for (int nf = 0; nf < 16; ++nf) {
      short8 bf = *(const short8*)(Wbf + (size_t)(nf * 16 + m) * IND + ko);
      acc[nf] = __builtin_amdgcn_mfma_f32_16x16x32_bf16(af, bf, acc[nf], 0, 0, 0);
    }
  }

  // bias + score dot-products (f32, pre-bf16-rounding)
  float p1[4] = {0, 0, 0, 0}, p2[4] = {0, 0, 0, 0};
#pragma unroll
  for (int nf = 0; nf < 16; ++nf) {
    const int n = nf * 16 + m;
    const float b = Wb[n], c1 = a1w[n], c2 = a2w[n];
#pragma unroll
    for (int r = 0; r < 4; ++r) {
      float v = acc[nf][r] + b;
      acc[nf][r] = v;
      p1[r] += c1 * v;
      p2[r] += c2 * v;
    }
  }
#pragma unroll
  for (int off = 1; off < 16; off <<= 1) {
#pragma unroll
    for (int r = 0; r < 4; ++r) {
      p1[r] += __shfl_xor(p1[r], off);
      p2[r] += __shfl_xor(p2[r], off);
    }
  }
  if (m == 0) {
    const float b1 = a1b[0], b2 = a2b[0];
#pragma unroll
    for (int r = 0; r < 4; ++r) {
      const int row = rowbase + g * 4 + r;
      s1[row] = p1[r] + b1;
      s2[row] = p2[r] + b2;
    }
  }

  // store Wh^T bf16: rows r=0..3 are contiguous columns of Wh^T -> 8B packs
#pragma unroll
  for (int nf = 0; nf < 16; ++nf) {
    short4v o;
#pragma unroll
    for (int r = 0; r < 4; ++r) o[r] = bf16_rne(acc[nf][r]);
    *(short4v*)(WhT + (size_t)(nf * 16 + m) * NN + rowbase + g * 4) = o;
  }
}

extern "C" __global__ __launch_bounds__(512) void k_attn(
    const int* __restrict__ mask, const short* __restrict__ WhT,
    const float* __restrict__ s1, const float* __restrict__ s2,
    float* __restrict__ out) {
  const int tid = threadIdx.x;
  const int w = tid >> 6, lane = tid & 63, g = lane >> 4, m = lane & 15;
  const int mg = w >> 2, ng = w & 3;  // 2 M-groups x 4 N-groups
  const int row = blockIdx.x * 32 + mg * 16 + m;
  const float s1r = s1[row];
  const int* mrow = mask + (size_t)row * NN;
  const short* wbase = WhT + (size_t)(ng * 64 + m) * NN;

  f32x4 acc[4];
#pragma unroll
  for (int nf = 0; nf < 4; ++nf) acc[nf] = (f32x4){0.f, 0.f, 0.f, 0.f};
  float den = 0.f;

  for (int j0 = 0; j0 < NN; j0 += 32) {
    const int jo = j0 + g * 8;
    f32x4 sa = *(const f32x4*)(s2 + jo);
    f32x4 sb = *(const f32x4*)(s2 + jo + 4);
    i32x4 ma = *(const i32x4*)(mrow + jo);
    i32x4 mb = *(const i32x4*)(mrow + jo + 4);
    short8 af;
#pragma unroll
    for (int i = 0; i < 8; ++i) {
      float sv = s1r + (i < 4 ? sa[i] : sb[i - 4]);
      sv = sv > 0.f ? sv : NEG_SLOPE * sv;
      float pv = ((i < 4 ? ma[i] : mb[i - 4]) != 0) ? __expf(sv) : 0.f;
      den += pv;
      af[i] = bf16_rne(pv);
    }
#pragma unroll
    for (int nf = 0; nf < 4; ++nf) {
      short8 bf = *(const short8*)(wbase + (size_t)nf * 16 * NN + jo);
      acc[nf] = __builtin_amdgcn_mfma_f32_16x16x32_bf16(af, bf, acc[nf], 0, 0, 0);
    }
  }

  // den: sum partials across the 4 k-groups (lanes with equal m)
  den += __shfl_xor(den, 16);
  den += __shfl_xor(den, 32);

#pragma unroll
  for (int r = 0; r < 4; ++r) {
    const int q = g * 4 + r;                 // local output row of this D reg
    const float inv = 1.0f / __shfl(den, q); // lane q holds den for row q
    const int orow = blockIdx.x * 32 + mg * 16 + q;
#pragma unroll
    for (int nf = 0; nf < 4; ++nf) {
      out[(size_t)orow * OUTD + ng * 64 + nf * 16 + m] = acc[nf][r] * inv;
    }
  }
}

extern "C" void kernel_launch(void* const* d_in, const int* in_sizes, int n_in,
                              void* d_out, int out_size, void* d_ws, size_t ws_size,
                              hipStream_t stream) {
  const float* nodes = (const float*)d_in[0];
  const int*   mask  = (const int*)d_in[1];
  const float* W_w   = (const float*)d_in[2];
  const float* W_b   = (const float*)d_in[3];
  const float* a1w   = (const float*)d_in[4];
  const float* a1b   = (const float*)d_in[5];
  const float* a2w   = (const float*)d_in[6];
  const float* a2b   = (const float*)d_in[7];
  float* out = (float*)d_out;

  char* ws = (char*)d_ws;
  short* WhT = (short*)(ws);                                   // 4 MiB
  float* s1  = (float*)(ws + (size_t)4 * 1024 * 1024);         // 32 KiB
  float* s2  = (float*)(ws + (size_t)4 * 1024 * 1024 + 32768); // 32 KiB
  short* Wbf = (short*)(ws + (size_t)4 * 1024 * 1024 + 65536); // 256 KiB

  hipLaunchKernelGGL(k_convert_w, dim3(128), dim3(256), 0, stream, W_w, Wbf);
  hipLaunchKernelGGL(k_wh, dim3(256), dim3(128), 0, stream,
                     nodes, Wbf, W_b, a1w, a1b, a2w, a2b, WhT, s1, s2);
  hipLaunchKernelGGL(k_attn, dim3(256), dim3(512), 0, stream,
                     mask, WhT, s1, s2, out);
}

// Round 2
// 177.989 us; speedup vs baseline: 2.5703x; 2.5703x over previous
//
#include <hip/hip_runtime.h>
#include <hip/hip_bf16.h>
#include <stdint.h>

// DenseGraphAttentionHead N=8192, IN=512, OUT=256, ~50% dense int32 mask.
//
// k_convert_w: W f32[256][512] -> bf16 chunked layout W2: 16B chunk (kb,row)
//              = W[row][kb*8..kb*8+7], short offset kb*2048 + row*8.
// k_wh:        Wh = nodes@W^T + b (mfma 16x16x32 bf16). Outputs:
//              WhL chunked bf16: chunk (jb,n) = Wh[jb*8..+7][n] at short
//              offset jb*2048 + n*8  (B-frag = 1 base + nf*256B immediates),
//              s1/s2 f32[8192] from the f32 accumulator.
// k_attn:      fused masked-softmax @ Wh. Scores bounded (|s|<~5) -> exp
//              without max subtraction, single pass. Block = 512 thr =
//              8 waves, ALL waves same 32 rows, wave w owns j-chunk
//              [w*1024,(w+1)*1024). Per wave: BM=32 (2 A-frags) x nf=16,
//              per 32-j substep: build P in-register from nontemporal mask
//              loads (prefetched 1 deep) -> 32 MFMA. Partials combined via
//              3-phase LDS tree, divide by den in epilogue. No barriers in
//              the main loop.
//
// MFMA conventions (verified in R1 on this problem):
//   A frag: lane&15 = m, k = (lane>>4)*8 + i ; B same k order
//   D: col = lane&15, row = (lane>>4)*4 + reg

#define NN 8192
#define IND 512
#define OUTD 256

typedef __attribute__((ext_vector_type(8))) short short8;
typedef __attribute__((ext_vector_type(4))) short short4v;
typedef __attribute__((ext_vector_type(4))) float f32x4;
typedef __attribute__((ext_vector_type(4))) int i32x4;

static __device__ __forceinline__ short f2bf(float f) {
  return __builtin_bit_cast(short, __float2bfloat16(f));
}

extern "C" __global__ __launch_bounds__(256) void k_convert_w(
    const float* __restrict__ W, short* __restrict__ W2) {
  const int t = blockIdx.x * 256 + threadIdx.x;  // 16384 threads
  const int row = t >> 6, kb = t & 63;
  const float* src = W + row * IND + kb * 8;
  f32x4 x0 = *(const f32x4*)src;
  f32x4 x1 = *(const f32x4*)(src + 4);
  short8 o;
  o[0] = f2bf(x0[0]); o[1] = f2bf(x0[1]); o[2] = f2bf(x0[2]); o[3] = f2bf(x0[3]);
  o[4] = f2bf(x1[0]); o[5] = f2bf(x1[1]); o[6] = f2bf(x1[2]); o[7] = f2bf(x1[3]);
  *(short8*)(W2 + (size_t)kb * 2048 + row * 8) = o;
}

extern "C" __global__ __launch_bounds__(128) void k_wh(
    const float* __restrict__ nodes, const short* __restrict__ W2,
    const float* __restrict__ Wb, const float* __restrict__ a1w,
    const float* __restrict__ a1b, const float* __restrict__ a2w,
    const float* __restrict__ a2b, short* __restrict__ WhL,
    float* __restrict__ s1, float* __restrict__ s2) {
  const int tid = threadIdx.x;
  const int wv = tid >> 6, lane = tid & 63, g = lane >> 4, m = lane & 15;
  const int rowbase = blockIdx.x * 32 + wv * 16;

  f32x4 acc[16];
#pragma unroll
  for (int nf = 0; nf < 16; ++nf) acc[nf] = (f32x4){0.f, 0.f, 0.f, 0.f};

  const float* arow = nodes + (size_t)(rowbase + m) * IND;
  const short* bb = W2 + (size_t)g * 2048 + m * 8;
#pragma unroll 4
  for (int k0 = 0; k0 < IND; k0 += 32) {
    const float* ap = arow + k0 + g * 8;
    f32x4 x0 = *(const f32x4*)ap;
    f32x4 x1 = *(const f32x4*)(ap + 4);
    short8 af;
    af[0] = f2bf(x0[0]); af[1] = f2bf(x0[1]); af[2] = f2bf(x0[2]); af[3] = f2bf(x0[3]);
    af[4] = f2bf(x1[0]); af[5] = f2bf(x1[1]); af[6] = f2bf(x1[2]); af[7] = f2bf(x1[3]);
    const short* bk = bb + (size_t)(k0 >> 3) * 2048;
#pragma unroll
    for (int nf = 0; nf < 16; ++nf) {
      short8 bf = *(const short8*)(bk + nf * 128);
      acc[nf] = __builtin_amdgcn_mfma_f32_16x16x32_bf16(af, bf, acc[nf], 0, 0, 0);
    }
  }

  float p1[4] = {0.f, 0.f, 0.f, 0.f}, p2[4] = {0.f, 0.f, 0.f, 0.f};
#pragma unroll
  for (int nf = 0; nf < 16; ++nf) {
    const int n = nf * 16 + m;
    const float b = Wb[n], c1 = a1w[n], c2 = a2w[n];
#pragma unroll
    for (int r = 0; r < 4; ++r) {
      float v = acc[nf][r] + b;
      acc[nf][r] = v;
      p1[r] += c1 * v;
      p2[r] += c2 * v;
    }
  }
#pragma unroll
  for (int off = 1; off < 16; off <<= 1) {
#pragma unroll
    for (int r = 0; r < 4; ++r) {
      p1[r] += __shfl_xor(p1[r], off);
      p2[r] += __shfl_xor(p2[r], off);
    }
  }
  if (m == 0) {
    const float b1 = a1b[0], b2 = a2b[0];
#pragma unroll
    for (int r = 0; r < 4; ++r) {
      const int row = rowbase + g * 4 + r;
      s1[row] = p1[r] + b1;
      s2[row] = p2[r] + b2;
    }
  }

  // WhL store: Wh row = rowbase + g*4 + r, col n = nf*16+m
  // chunk jb = (rowbase + g*4)/8 = rowbase/8 + (g>>1), slot = (g&1)*4 + r
  const size_t cbase = ((size_t)(rowbase >> 3) + (g >> 1)) * 2048 + (g & 1) * 4;
#pragma unroll
  for (int nf = 0; nf < 16; ++nf) {
    short4v o;
#pragma unroll
    for (int r = 0; r < 4; ++r) o[r] = f2bf(acc[nf][r]);
    *(short4v*)(WhL + cbase + (size_t)(nf * 16 + m) * 8) = o;
  }
}

extern "C" __global__ __launch_bounds__(512, 2) void k_attn(
    const int* __restrict__ mask, const short* __restrict__ WhL,
    const float* __restrict__ s1, const float* __restrict__ s2,
    float* __restrict__ out) {
  __shared__ f32x4 cbuf[3][64][32];  // 96 KiB combine buffers
  __shared__ float denl[8][32];      // 1 KiB

  const int tid = threadIdx.x;
  const int w = tid >> 6, lane = tid & 63, g = lane >> 4, m = lane & 15;
  const int rg = blockIdx.x * 32;

  const float s1a = s1[rg + m];
  const float s1b = s1[rg + 16 + m];

  f32x4 acc0[16], acc1[16];
#pragma unroll
  for (int nf = 0; nf < 16; ++nf) {
    acc0[nf] = (f32x4){0.f, 0.f, 0.f, 0.f};
    acc1[nf] = (f32x4){0.f, 0.f, 0.f, 0.f};
  }
  float den0 = 0.f, den1 = 0.f;

  const int* mr0 = mask + (size_t)(rg + m) * NN + w * 1024 + g * 8;
  const int* mr1 = mr0 + (size_t)16 * NN;
  const float* sp = s2 + w * 1024 + g * 8;
  const short* bb = WhL + ((size_t)w * 128 + g) * 2048 + (size_t)m * 8;

  // 1-deep prefetch of the HBM streams (mask rows m and m+16, s2 slice)
  i32x4 ca0 = __builtin_nontemporal_load((const i32x4*)mr0);
  i32x4 ca1 = __builtin_nontemporal_load((const i32x4*)(mr0 + 4));
  i32x4 cb0 = __builtin_nontemporal_load((const i32x4*)mr1);
  i32x4 cb1 = __builtin_nontemporal_load((const i32x4*)(mr1 + 4));
  f32x4 cs0 = *(const f32x4*)sp;
  f32x4 cs1 = *(const f32x4*)(sp + 4);

  auto build = [&](float s1h, const i32x4& xlo, const i32x4& xhi,
                   const f32x4& slo, const f32x4& shi, float& den) -> short8 {
    short8 af;
#pragma unroll
    for (int i = 0; i < 4; ++i) {
      float sv = s1h + slo[i];
      sv = fmaxf(sv, 0.2f * sv);           // leaky-relu (slope 0.2 > 0)
      float pv = (xlo[i] != 0) ? __expf(sv) : 0.f;
      den += pv;
      af[i] = f2bf(pv);
    }
#pragma unroll
    for (int i = 0; i < 4; ++i) {
      float sv = s1h + shi[i];
      sv = fmaxf(sv, 0.2f * sv);
      float pv = (xhi[i] != 0) ? __expf(sv) : 0.f;
      den += pv;
      af[i + 4] = f2bf(pv);
    }
    return af;
  };

#pragma unroll 2
  for (int u = 0; u < 32; ++u) {
    const int un = (u < 31) ? (u + 1) : 31;  // clamp: avoid OOB on last row
    i32x4 na0 = __builtin_nontemporal_load((const i32x4*)(mr0 + un * 32));
    i32x4 na1 = __builtin_nontemporal_load((const i32x4*)(mr0 + un * 32 + 4));
    i32x4 nb0 = __builtin_nontemporal_load((const i32x4*)(mr1 + un * 32));
    i32x4 nb1 = __builtin_nontemporal_load((const i32x4*)(mr1 + un * 32 + 4));
    f32x4 ns0 = *(const f32x4*)(sp + un * 32);
    f32x4 ns1 = *(const f32x4*)(sp + un * 32 + 4);

    short8 af0 = build(s1a, ca0, ca1, cs0, cs1, den0);
    short8 af1 = build(s1b, cb0, cb1, cs0, cs1, den1);

    const short* bu = bb + (size_t)u * 8192;  // 32 j's = 4 chunks = 16 KiB
#pragma unroll
    for (int nf = 0; nf < 16; ++nf) {
      short8 bf = *(const short8*)(bu + nf * 128);
      acc0[nf] = __builtin_amdgcn_mfma_f32_16x16x32_bf16(af0, bf, acc0[nf], 0, 0, 0);
      acc1[nf] = __builtin_amdgcn_mfma_f32_16x16x32_bf16(af1, bf, acc1[nf], 0, 0, 0);
    }
    ca0 = na0; ca1 = na1; cb0 = nb0; cb1 = nb1; cs0 = ns0; cs1 = ns1;
  }

  // den: sum across the 4 k-groups -> every lane holds its row-m totals
  den0 += __shfl_xor(den0, 16); den0 += __shfl_xor(den0, 32);
  den1 += __shfl_xor(den1, 16); den1 += __shfl_xor(den1, 32);
  if (lane < 16) { denl[w][m] = den0; denl[w][16 + m] = den1; }

  // XOR-swizzled combine buffers: chunk c for lane at cbuf[b][lane][c^(lane&7)]
  auto storeacc = [&](int b) {
#pragma unroll
    for (int nf = 0; nf < 16; ++nf) {
      cbuf[b][lane][nf ^ (lane & 7)] = acc0[nf];
      cbuf[b][lane][(16 + nf) ^ (lane & 7)] = acc1[nf];
    }
  };
  auto addacc = [&](int b) {
#pragma unroll
    for (int nf = 0; nf < 16; ++nf) {
      acc0[nf] += cbuf[b][lane][nf ^ (lane & 7)];
      acc1[nf] += cbuf[b][lane][(16 + nf) ^ (lane & 7)];
    }
  };

  // 3-phase tree: w0 ends with the sum of all 8 waves
  __syncthreads();
  if (w >= 4 && w <= 6) storeacc(w - 4);
  __syncthreads();
  if (w < 3) addacc(w);            // w0+=w4, w1+=w5, w2+=w6
  __syncthreads();
  if (w == 7) storeacc(0);
  if (w == 3) storeacc(1);
  __syncthreads();
  if (w == 0) addacc(0);           // w0+=w7
  if (w == 1) addacc(1);           // w1+=w3
  __syncthreads();
  if (w == 1) storeacc(0);
  if (w == 2) storeacc(1);
  __syncthreads();
  if (w == 0) {
    addacc(0);                     // += (w1+w5+w3)
    addacc(1);                     // += (w2+w6)
    float d0 = 0.f, d1 = 0.f;
#pragma unroll
    for (int ww = 0; ww < 8; ++ww) { d0 += denl[ww][m]; d1 += denl[ww][16 + m]; }
#pragma unroll
    for (int r = 0; r < 4; ++r) {
      const int q = g * 4 + r;
      const float i0 = 1.f / __shfl(d0, q);
      const float i1 = 1.f / __shfl(d1, q);
#pragma unroll
      for (int nf = 0; nf < 16; ++nf) {
        out[(size_t)(rg + q) * OUTD + nf * 16 + m] = acc0[nf][r] * i0;
        out[(size_t)(rg + 16 + q) * OUTD + nf * 16 + m] = acc1[nf][r] * i1;
      }
    }
  }
}

extern "C" void kernel_launch(void* const* d_in, const int* in_sizes, int n_in,
                              void* d_out, int out_size, void* d_ws, size_t ws_size,
                              hipStream_t stream) {
  const float* nodes = (const float*)d_in[0];
  const int*   mask  = (const int*)d_in[1];
  const float* W_w   = (const float*)d_in[2];
  const float* W_b   = (const float*)d_in[3];
  const float* a1w   = (const float*)d_in[4];
  const float* a1b   = (const float*)d_in[5];
  const float* a2w   = (const float*)d_in[6];
  const float* a2b   = (const float*)d_in[7];
  float* out = (float*)d_out;

  char* ws = (char*)d_ws;
  short* WhL = (short*)(ws);                                    // 4 MiB
  float* s1  = (float*)(ws + (size_t)4 * 1024 * 1024);          // 32 KiB
  float* s2  = (float*)(ws + (size_t)4 * 1024 * 1024 + 32768);  // 32 KiB
  short* W2  = (short*)(ws + (size_t)4 * 1024 * 1024 + 65536);  // 256 KiB

  hipLaunchKernelGGL(k_convert_w, dim3(64), dim3(256), 0, stream, W_w, W2);
  hipLaunchKernelGGL(k_wh, dim3(256), dim3(128), 0, stream,
                     nodes, W2, W_b, a1w, a1b, a2w, a2b, WhL, s1, s2);
  hipLaunchKernelGGL(k_attn, dim3(256), dim3(512), 0, stream,
                     mask, WhL, s1, s2, out);
}